// Round 6
// baseline (335.160 us; speedup 1.0000x reference)
//
#include <hip/hip_runtime.h>

// GraphSAGE: 3x (project -> mean-aggregate) + mean pool + log_softmax.
// Project-then-aggregate reorder: agg(h) @ Wl == agg(h @ Wl).
// R6: XCD-partitioned CSR build — 8 (cnt,colbuf) copies, copy = blockIdx&7
//     (= XCD on round-robin dispatch). Atomic RMWs and scatter stores become
//     XCD-local (no cross-XCD line ping-pong); aggregators sum 8 copies.

#define CCAP 16          // per-copy bucket capacity (per-copy deg ~ Poisson(2))

typedef __attribute__((ext_vector_type(8))) short short8;
typedef __attribute__((ext_vector_type(4))) float floatx4;

static __device__ __forceinline__ unsigned short f2bf(float f) {
    unsigned int u = __float_as_uint(f);
    u += 0x7FFFu + ((u >> 16) & 1u);          // round-to-nearest-even
    return (unsigned short)(u >> 16);
}
static __device__ __forceinline__ float bf2f(unsigned short b) {
    return __uint_as_float(((unsigned int)b) << 16);
}

// ---------------- weight prepack (blocks 0..255) + workspace zeroing (tail) ----
__global__ void prep_weights(const float* __restrict__ Wl1, const float* __restrict__ Wr1,
                             const float* __restrict__ Wl2, const float* __restrict__ Wr2,
                             short* __restrict__ Wp,
                             int* __restrict__ zero_base, int zero_words) {
    if (blockIdx.x >= 256) {
        int i = (blockIdx.x - 256) * 256 + threadIdx.x;
        if (i < zero_words) zero_base[i] = 0;
        return;
    }
    int idx = blockIdx.x * 256 + threadIdx.x;      // 65536 total
    int layer = idx >> 15;
    int r = idx & 32767;
    int j = r & 7;
    int l = (r >> 3) & 63;
    int s = (r >> 9) & 3;
    int mf = r >> 11;
    int q = l >> 4, m = l & 15;
    int k = s * 32 + q * 8 + j;
    int f = mf * 16 + m;
    const float* Wl = layer ? Wl2 : Wl1;
    const float* Wr = layer ? Wr2 : Wr1;
    float v = (f < 128) ? Wl[k * 128 + f] : Wr[k * 128 + (f - 128)];
    Wp[idx] = (short)f2bf(v);
}

// ---------------- MFMA GEMM body: [msg|base][node][128] = A[node][128] @ W[128][256] ----
template<bool IN_F32>
static __device__ __forceinline__ void gemm_body(
    unsigned short* As /* [64*136] */, const void* __restrict__ Ain,
    const short* __restrict__ Wpack, const float* __restrict__ bl,
    unsigned short* __restrict__ msg, unsigned short* __restrict__ base,
    int N, int blk) {
    const int tid = threadIdx.x;
    const int w = tid >> 6;
    const int l = tid & 63;
    const int q = l >> 4;
    const int m = l & 15;
    const int node0 = blk * 64;

    short8 wf[4][4];   // [mi][s]
#pragma unroll
    for (int mi = 0; mi < 4; ++mi)
#pragma unroll
        for (int s = 0; s < 4; ++s)
            wf[mi][s] = *(const short8*)&Wpack[((((w * 4 + mi) * 4) + s) * 64 + l) * 8];

    if (IN_F32) {
        const float* A = (const float*)Ain;
#pragma unroll
        for (int c = 0; c < 8; ++c) {
            int idx = c * 256 + tid;
            int r = idx >> 5;
            int c4 = idx & 31;
            int row = node0 + r;
            float4 v = make_float4(0.f, 0.f, 0.f, 0.f);
            if (row < N) v = *(const float4*)&A[(size_t)row * 128 + c4 * 4];
            ushort4 p;
            p.x = f2bf(v.x); p.y = f2bf(v.y); p.z = f2bf(v.z); p.w = f2bf(v.w);
            *(ushort4*)&As[r * 136 + c4 * 4] = p;
        }
    } else {
        const unsigned short* A = (const unsigned short*)Ain;
#pragma unroll
        for (int c = 0; c < 4; ++c) {
            int idx = c * 256 + tid;
            int r = idx >> 4;
            int c8 = idx & 15;
            int row = node0 + r;
            short8 v = (short8)0;
            if (row < N) v = *(const short8*)&A[(size_t)row * 128 + c8 * 8];
            *(short8*)&As[r * 136 + c8 * 8] = v;
        }
    }
    __syncthreads();

    floatx4 acc[4][4] = {};    // [mi][nt]
#pragma unroll
    for (int s = 0; s < 4; ++s) {
        short8 bfrag[4];
#pragma unroll
        for (int nt = 0; nt < 4; ++nt)
            bfrag[nt] = *(const short8*)&As[(nt * 16 + m) * 136 + s * 32 + q * 8];
#pragma unroll
        for (int mi = 0; mi < 4; ++mi)
#pragma unroll
            for (int nt = 0; nt < 4; ++nt)
                acc[mi][nt] = __builtin_amdgcn_mfma_f32_16x16x32_bf16(
                    wf[mi][s], bfrag[nt], acc[mi][nt], 0, 0, 0);
    }

#pragma unroll
    for (int mi = 0; mi < 4; ++mi) {
        int f0 = (w * 4 + mi) * 16 + q * 4;
        if (w < 2) {
#pragma unroll
            for (int nt = 0; nt < 4; ++nt) {
                int node = node0 + nt * 16 + m;
                if (node >= N) continue;
                floatx4 a = acc[mi][nt];
                ushort4 p;
                p.x = f2bf(a[0]); p.y = f2bf(a[1]); p.z = f2bf(a[2]); p.w = f2bf(a[3]);
                *(ushort4*)&msg[(size_t)node * 128 + f0] = p;
            }
        } else {
            int fb = f0 - 128;
            float4 bb = *(const float4*)&bl[fb];
#pragma unroll
            for (int nt = 0; nt < 4; ++nt) {
                int node = node0 + nt * 16 + m;
                if (node >= N) continue;
                floatx4 a = acc[mi][nt];
                ushort4 p;
                p.x = f2bf(a[0] + bb.x); p.y = f2bf(a[1] + bb.y);
                p.z = f2bf(a[2] + bb.z); p.w = f2bf(a[3] + bb.w);
                *(ushort4*)&base[(size_t)node * 128 + fb] = p;
            }
        }
    }
}

// layer-1 GEMM with edge-fill blocks FIRST; fill writes XCD-local CSR copy.
__global__ __launch_bounds__(256) void gemm1_fill(
    const float* __restrict__ x, const short* __restrict__ Wpack,
    const float* __restrict__ bl, unsigned short* __restrict__ msg,
    unsigned short* __restrict__ base, int N, int fblocks,
    const int* __restrict__ ei, int* __restrict__ cnt8,
    unsigned short* __restrict__ colbuf8, int E) {
    __shared__ unsigned short As[64 * 136];
    if (blockIdx.x >= fblocks) {
        gemm_body<true>(As, x, Wpack, bl, msg, base, N, blockIdx.x - fblocks);
    } else {
        int copy = blockIdx.x & 7;                    // = XCD on round-robin dispatch
        int* cnt = cnt8 + (size_t)copy * N;
        unsigned short* colbuf = colbuf8 + (size_t)copy * N * CCAP;
        int e0 = blockIdx.x * 1024 + threadIdx.x;     // 4 edges per thread
        int src[4], dst[4];
#pragma unroll
        for (int k = 0; k < 4; ++k) {
            int e = e0 + k * 256;
            bool ok = e < E;
            src[k] = ok ? ei[e] : -1;
            dst[k] = ok ? ei[E + e] : 0;
        }
#pragma unroll
        for (int k = 0; k < 4; ++k) {
            if (src[k] >= 0) {
                int slot = atomicAdd(&cnt[dst[k]], 1);
                if (slot < CCAP) colbuf[dst[k] * CCAP + slot] = (unsigned short)src[k];
            }
        }
    }
}

__global__ __launch_bounds__(256) void gemm_mfma_bf16(
    const unsigned short* __restrict__ Ain, const short* __restrict__ Wpack,
    const float* __restrict__ bl, unsigned short* __restrict__ msg,
    unsigned short* __restrict__ base, int N) {
    __shared__ unsigned short As[64 * 136];
    gemm_body<false>(As, Ain, Wpack, bl, msg, base, N, blockIdx.x);
}

// ---------------- aggregate 128-dim: wave per node, 8 CSR copies ----------
// Lane-packed index preload: idxA holds copies 0-3 (lane = copy*16+slot),
// idxB copies 4-7. All gathers independent.
__global__ __launch_bounds__(256) void agg128(
    const unsigned int* __restrict__ msg32, const int* __restrict__ cnt8,
    const unsigned short* __restrict__ colbuf8, const unsigned int* __restrict__ base32,
    unsigned int* __restrict__ hout32, int N) {
    int lane = threadIdx.x & 63;
    int node = blockIdx.x * 4 + (threadIdx.x >> 6);
    if (node >= N) return;

    int dcv = (lane < 8) ? cnt8[(size_t)lane * N + node] : 0;
    int deg = 0;
#pragma unroll
    for (int c = 0; c < 8; ++c) deg += __shfl(dcv, c, 64);

    int cA = lane >> 4, sA = lane & 15;
    int dA = min(__shfl(dcv, cA, 64), CCAP);
    int dB = min(__shfl(dcv, cA + 4, 64), CCAP);
    int idxA = (sA < dA) ? (int)colbuf8[((size_t)cA * N + node) * CCAP + sA] : 0;
    int idxB = (sA < dB) ? (int)colbuf8[((size_t)(cA + 4) * N + node) * CCAP + sA] : 0;

    float acc0 = 0.f, acc1 = 0.f;
#pragma unroll
    for (int c = 0; c < 8; ++c) {
        int dc = min(__shfl(dcv, c, 64), CCAP);
        int bs = (c & 3) * 16;
        int reg = (c < 4) ? idxA : idxB;
        for (int k = 0; k < dc; ++k) {
            int s = __shfl(reg, bs + k, 64);
            unsigned int v = msg32[(size_t)s * 64 + lane];
            acc0 += __uint_as_float(v << 16);
            acc1 += __uint_as_float(v & 0xFFFF0000u);
        }
    }
    float inv = 1.0f / (float)max(deg, 1);
    unsigned int bu = base32[(size_t)node * 64 + lane];
    float o0 = acc0 * inv + __uint_as_float(bu << 16);
    float o1 = acc1 * inv + __uint_as_float(bu & 0xFFFF0000u);
    hout32[(size_t)node * 64 + lane] =
        (unsigned int)f2bf(o0) | ((unsigned int)f2bf(o1) << 16);
}

// ---------------- layer-3 GEMM: T3[N,20] = h(bf16)[N,128] @ [Wl3 | Wr3] ----------
__global__ __launch_bounds__(256) void gemm3(
    const unsigned short* __restrict__ h, const float* __restrict__ Wl,
    const float* __restrict__ Wr, float* __restrict__ t3, int N) {
    __shared__ float hs[64][136];
    __shared__ float Ws[128][20];
    const int tid = threadIdx.x;
    const int row0 = blockIdx.x * 64;
    for (int i = tid; i < 128 * 20; i += 256) {
        int k = i / 20, c = i % 20;
        Ws[k][c] = (c < 10) ? Wl[k * 10 + c] : Wr[k * 10 + (c - 10)];
    }
#pragma unroll
    for (int ch = 0; ch < 4; ++ch) {
        int idx = ch * 256 + tid;
        int r = idx >> 4;
        int c8 = idx & 15;
        int row = row0 + r;
        short8 v = (short8)0;
        if (row < N) v = *(const short8*)&h[(size_t)row * 128 + c8 * 8];
#pragma unroll
        for (int i = 0; i < 8; ++i)
            hs[r][c8 * 8 + i] = bf2f((unsigned short)v[i]);
    }
    __syncthreads();
    for (int i = tid; i < 64 * 20; i += 256) {
        int r = i / 20, c = i % 20;
        int row = row0 + r;
        if (row >= N) continue;
        float acc = 0.f;
#pragma unroll 16
        for (int k = 0; k < 128; ++k) acc += hs[r][k] * Ws[k][c];
        t3[(size_t)row * 20 + c] = acc;
    }
}

// ---------------- aggregate 10-dim, 8 CSR copies ----------------
__global__ void agg10(const float* __restrict__ t3, const int* __restrict__ cnt8,
                      const unsigned short* __restrict__ colbuf8, const float* __restrict__ bl3,
                      float* __restrict__ h3, int N) {
    int gid = blockIdx.x * blockDim.x + threadIdx.x;
    if (gid >= N * 10) return;
    int n = gid / 10, c = gid % 10;
    int deg = 0;
    float acc = 0.f;
#pragma unroll
    for (int cp = 0; cp < 8; ++cp) {
        int dc = cnt8[(size_t)cp * N + n];
        deg += dc;
        dc = min(dc, CCAP);
        const unsigned short* cb = &colbuf8[((size_t)cp * N + n) * CCAP];
        for (int k = 0; k < dc; ++k) acc += t3[(size_t)cb[k] * 20 + c];
    }
    h3[gid] = acc / (float)max(deg, 1) + bl3[c] + t3[(size_t)n * 20 + 10 + c];
}

// ---------------- pooling ----------------
__global__ __launch_bounds__(256) void pool(
    const float* __restrict__ h3, const int* __restrict__ batch,
    float* __restrict__ gsum, float* __restrict__ gcnt, int N) {
    __shared__ float ls[256 * 10 + 256];
    for (int i = threadIdx.x; i < 2816; i += 256) ls[i] = 0.f;
    __syncthreads();
    int n = blockIdx.x * 256 + threadIdx.x;
    if (n < N) {
        int g = batch[n];
#pragma unroll
        for (int c = 0; c < 10; ++c) atomicAdd(&ls[g * 10 + c], h3[n * 10 + c]);
        atomicAdd(&ls[2560 + g], 1.0f);
    }
    __syncthreads();
    for (int i = threadIdx.x; i < 2816; i += 256) {
        float v = ls[i];
        if (v != 0.f) {
            if (i < 2560) atomicAdd(&gsum[i], v);
            else          atomicAdd(&gcnt[i - 2560], v);
        }
    }
}

// ---------------- mean + log_softmax ----------------
__global__ void finalize_pool(const float* __restrict__ gsum,
                              const float* __restrict__ gcnt,
                              float* __restrict__ out, int G) {
    int g = blockIdx.x * blockDim.x + threadIdx.x;
    if (g >= G) return;
    float inv = 1.0f / fmaxf(gcnt[g], 1.0f);
    float p[10];
    float m = -1e30f;
#pragma unroll
    for (int c = 0; c < 10; ++c) { p[c] = gsum[g * 10 + c] * inv; m = fmaxf(m, p[c]); }
    float s = 0.f;
#pragma unroll
    for (int c = 0; c < 10; ++c) s += expf(p[c] - m);
    float lse = logf(s);
#pragma unroll
    for (int c = 0; c < 10; ++c) out[g * 10 + c] = p[c] - m - lse;
}

extern "C" void kernel_launch(void* const* d_in, const int* in_sizes, int n_in,
                              void* d_out, int out_size, void* d_ws, size_t ws_size,
                              hipStream_t stream) {
    const float* x    = (const float*)d_in[0];
    const int*   ei   = (const int*)d_in[1];
    const int*   batch= (const int*)d_in[2];
    const float* Wl1  = (const float*)d_in[3];
    const float* bl1  = (const float*)d_in[4];
    const float* Wr1  = (const float*)d_in[5];
    const float* Wl2  = (const float*)d_in[6];
    const float* bl2  = (const float*)d_in[7];
    const float* Wr2  = (const float*)d_in[8];
    const float* Wl3  = (const float*)d_in[9];
    const float* bl3  = (const float*)d_in[10];
    const float* Wr3  = (const float*)d_in[11];
    float* out = (float*)d_out;

    const int N = in_sizes[2];
    const int E = in_sizes[1] / 2;
    const int G = out_size / 10;

    char* ws = (char*)d_ws;
    size_t o = 0;
    int*   cnt8   = (int*)(ws + o);   o += (size_t)8 * N * 4;        // 1.6 MB
    float* gsum   = (float*)(ws + o); o += (size_t)G * 10 * 4;
    float* gcnt   = (float*)(ws + o); o += (size_t)G * 4;
    size_t zero_bytes = (o + 255) & ~(size_t)255;
    o = zero_bytes;
    unsigned short* colbuf8 = (unsigned short*)(ws + o); o += ((size_t)8 * N * CCAP * 2 + 255) & ~(size_t)255; // 12.8 MB
    short*          Wp      = (short*)(ws + o);          o += (size_t)2 * 32768 * 2;                           // 128 KB
    unsigned short* msg     = (unsigned short*)(ws + o); o += (size_t)N * 128 * 2;                             // 12.8 MB
    unsigned short* base    = (unsigned short*)(ws + o); o += (size_t)N * 128 * 2;                             // 12.8 MB
    unsigned short* hbuf    = (unsigned short*)(ws + o); o += (size_t)N * 128 * 2;                             // 12.8 MB
    float*          t3      = (float*)base;              // base dead after layer-2 agg (4 MB fits)
    float*          h3      = (float*)msg;               // msg dead after layer-2 agg (2 MB fits)

    int zero_words = (int)(zero_bytes / 4);
    int zblocks = (zero_words + 255) / 256;
    prep_weights<<<256 + zblocks, 256, 0, stream>>>(Wl1, Wr1, Wl2, Wr2, Wp,
                                                    (int*)ws, zero_words);

    int gblocks = (N + 63) / 64;
    int fblocks = (E + 1023) / 1024;
    // layer 1: fill blocks first, then GEMM blocks
    gemm1_fill<<<fblocks + gblocks, 256, 0, stream>>>(x, Wp, bl1, msg, base, N, fblocks,
                                                      ei, cnt8, colbuf8, E);
    agg128<<<(N + 3) / 4, 256, 0, stream>>>((const unsigned int*)msg, cnt8, colbuf8,
                                            (const unsigned int*)base, (unsigned int*)hbuf, N);
    // layer 2
    gemm_mfma_bf16<<<gblocks, 256, 0, stream>>>(hbuf, Wp + 32768, bl2, msg, base, N);
    agg128<<<(N + 3) / 4, 256, 0, stream>>>((const unsigned int*)msg, cnt8, colbuf8,
                                            (const unsigned int*)base, (unsigned int*)hbuf, N);
    // layer 3
    gemm3<<<gblocks, 256, 0, stream>>>(hbuf, Wl3, Wr3, t3, N);
    agg10<<<(N * 10 + 255) / 256, 256, 0, stream>>>(t3, cnt8, colbuf8, bl3, h3, N);
    // pool + log_softmax
    pool<<<(N + 255) / 256, 256, 0, stream>>>(h3, batch, gsum, gcnt, N);
    finalize_pool<<<1, 256, 0, stream>>>(gsum, gcnt, out, G);
}

// Round 7
// 320.870 us; speedup vs baseline: 1.0445x; 1.0445x over previous
//
#include <hip/hip_runtime.h>

// GraphSAGE: 3x (project -> mean-aggregate) + mean pool + log_softmax.
// Project-then-aggregate reorder: agg(h) @ Wl == agg(h @ Wl).
// R7: revert R6 partitioned CSR (regressed both fill and agg; atomic wall is
//     ~16G/s regardless of layout). Keep R5 single-copy CSR + fill-first
//     fusion. New: gemm3 fused into layer-2 agg128 (h2 never hits HBM),
//     agg10 fused into pool, 16-deep gather pipeline.

#define CAP 48

typedef __attribute__((ext_vector_type(8))) short short8;
typedef __attribute__((ext_vector_type(4))) float floatx4;

static __device__ __forceinline__ unsigned short f2bf(float f) {
    unsigned int u = __float_as_uint(f);
    u += 0x7FFFu + ((u >> 16) & 1u);          // round-to-nearest-even
    return (unsigned short)(u >> 16);
}

// ---------------- weight prepack (blocks 0..255) + workspace zeroing (tail) ----
__global__ void prep_weights(const float* __restrict__ Wl1, const float* __restrict__ Wr1,
                             const float* __restrict__ Wl2, const float* __restrict__ Wr2,
                             short* __restrict__ Wp,
                             int* __restrict__ zero_base, int zero_words) {
    if (blockIdx.x >= 256) {
        int i = (blockIdx.x - 256) * 256 + threadIdx.x;
        if (i < zero_words) zero_base[i] = 0;
        return;
    }
    int idx = blockIdx.x * 256 + threadIdx.x;      // 65536 total
    int layer = idx >> 15;
    int r = idx & 32767;
    int j = r & 7;
    int l = (r >> 3) & 63;
    int s = (r >> 9) & 3;
    int mf = r >> 11;
    int q = l >> 4, m = l & 15;
    int k = s * 32 + q * 8 + j;
    int f = mf * 16 + m;
    const float* Wl = layer ? Wl2 : Wl1;
    const float* Wr = layer ? Wr2 : Wr1;
    float v = (f < 128) ? Wl[k * 128 + f] : Wr[k * 128 + (f - 128)];
    Wp[idx] = (short)f2bf(v);
}

// ---------------- MFMA GEMM body: [msg|base][node][128] = A[node][128] @ W[128][256] ----
template<bool IN_F32>
static __device__ __forceinline__ void gemm_body(
    unsigned short* As /* [64*136] */, const void* __restrict__ Ain,
    const short* __restrict__ Wpack, const float* __restrict__ bl,
    unsigned short* __restrict__ msg, unsigned short* __restrict__ base,
    int N, int blk) {
    const int tid = threadIdx.x;
    const int w = tid >> 6;
    const int l = tid & 63;
    const int q = l >> 4;
    const int m = l & 15;
    const int node0 = blk * 64;

    short8 wf[4][4];   // [mi][s]
#pragma unroll
    for (int mi = 0; mi < 4; ++mi)
#pragma unroll
        for (int s = 0; s < 4; ++s)
            wf[mi][s] = *(const short8*)&Wpack[((((w * 4 + mi) * 4) + s) * 64 + l) * 8];

    if (IN_F32) {
        const float* A = (const float*)Ain;
#pragma unroll
        for (int c = 0; c < 8; ++c) {
            int idx = c * 256 + tid;
            int r = idx >> 5;
            int c4 = idx & 31;
            int row = node0 + r;
            float4 v = make_float4(0.f, 0.f, 0.f, 0.f);
            if (row < N) v = *(const float4*)&A[(size_t)row * 128 + c4 * 4];
            ushort4 p;
            p.x = f2bf(v.x); p.y = f2bf(v.y); p.z = f2bf(v.z); p.w = f2bf(v.w);
            *(ushort4*)&As[r * 136 + c4 * 4] = p;
        }
    } else {
        const unsigned short* A = (const unsigned short*)Ain;
#pragma unroll
        for (int c = 0; c < 4; ++c) {
            int idx = c * 256 + tid;
            int r = idx >> 4;
            int c8 = idx & 15;
            int row = node0 + r;
            short8 v = (short8)0;
            if (row < N) v = *(const short8*)&A[(size_t)row * 128 + c8 * 8];
            *(short8*)&As[r * 136 + c8 * 8] = v;
        }
    }
    __syncthreads();

    floatx4 acc[4][4] = {};    // [mi][nt]
#pragma unroll
    for (int s = 0; s < 4; ++s) {
        short8 bfrag[4];
#pragma unroll
        for (int nt = 0; nt < 4; ++nt)
            bfrag[nt] = *(const short8*)&As[(nt * 16 + m) * 136 + s * 32 + q * 8];
#pragma unroll
        for (int mi = 0; mi < 4; ++mi)
#pragma unroll
            for (int nt = 0; nt < 4; ++nt)
                acc[mi][nt] = __builtin_amdgcn_mfma_f32_16x16x32_bf16(
                    wf[mi][s], bfrag[nt], acc[mi][nt], 0, 0, 0);
    }

#pragma unroll
    for (int mi = 0; mi < 4; ++mi) {
        int f0 = (w * 4 + mi) * 16 + q * 4;
        if (w < 2) {
#pragma unroll
            for (int nt = 0; nt < 4; ++nt) {
                int node = node0 + nt * 16 + m;
                if (node >= N) continue;
                floatx4 a = acc[mi][nt];
                ushort4 p;
                p.x = f2bf(a[0]); p.y = f2bf(a[1]); p.z = f2bf(a[2]); p.w = f2bf(a[3]);
                *(ushort4*)&msg[(size_t)node * 128 + f0] = p;
            }
        } else {
            int fb = f0 - 128;
            float4 bb = *(const float4*)&bl[fb];
#pragma unroll
            for (int nt = 0; nt < 4; ++nt) {
                int node = node0 + nt * 16 + m;
                if (node >= N) continue;
                floatx4 a = acc[mi][nt];
                ushort4 p;
                p.x = f2bf(a[0] + bb.x); p.y = f2bf(a[1] + bb.y);
                p.z = f2bf(a[2] + bb.z); p.w = f2bf(a[3] + bb.w);
                *(ushort4*)&base[(size_t)node * 128 + fb] = p;
            }
        }
    }
}

// layer-1 GEMM with edge-fill blocks FIRST in the grid
__global__ __launch_bounds__(256) void gemm1_fill(
    const float* __restrict__ x, const short* __restrict__ Wpack,
    const float* __restrict__ bl, unsigned short* __restrict__ msg,
    unsigned short* __restrict__ base, int N, int fblocks,
    const int* __restrict__ ei, int* __restrict__ cnt,
    unsigned short* __restrict__ colbuf, int E) {
    __shared__ unsigned short As[64 * 136];
    if (blockIdx.x >= fblocks) {
        gemm_body<true>(As, x, Wpack, bl, msg, base, N, blockIdx.x - fblocks);
    } else {
        int e0 = blockIdx.x * 1024 + threadIdx.x;    // 4 edges per thread
        int src[4], dst[4];
#pragma unroll
        for (int k = 0; k < 4; ++k) {
            int e = e0 + k * 256;
            bool ok = e < E;
            src[k] = ok ? ei[e] : -1;
            dst[k] = ok ? ei[E + e] : 0;
        }
#pragma unroll
        for (int k = 0; k < 4; ++k) {
            if (src[k] >= 0) {
                int slot = atomicAdd(&cnt[dst[k]], 1);
                if (slot < CAP) colbuf[dst[k] * CAP + slot] = (unsigned short)src[k];
            }
        }
    }
}

__global__ __launch_bounds__(256) void gemm_mfma_bf16(
    const unsigned short* __restrict__ Ain, const short* __restrict__ Wpack,
    const float* __restrict__ bl, unsigned short* __restrict__ msg,
    unsigned short* __restrict__ base, int N) {
    __shared__ unsigned short As[64 * 136];
    gemm_body<false>(As, Ain, Wpack, bl, msg, base, N, blockIdx.x);
}

// ---------------- layer-1 aggregate: wave per node, 16 gathers in flight ----
__global__ __launch_bounds__(256) void agg128(
    const unsigned int* __restrict__ msg32, const int* __restrict__ cnt,
    const unsigned short* __restrict__ colbuf, const unsigned int* __restrict__ base32,
    unsigned int* __restrict__ hout32, int N) {
    int lane = threadIdx.x & 63;
    int node = blockIdx.x * 4 + (threadIdx.x >> 6);
    if (node >= N) return;
    int deg = cnt[node];
    int d = min(deg, CAP);
    const unsigned short* cb = colbuf + (size_t)node * CAP;
    int myidx = (lane < d) ? (int)cb[lane] : 0;
    float acc0 = 0.f, acc1 = 0.f;
    int k = 0;
    for (; k + 16 <= d; k += 16) {             // 16 independent gathers in flight
#pragma unroll
        for (int j = 0; j < 16; ++j) {
            int s = __shfl(myidx, k + j, 64);
            unsigned int v = msg32[(size_t)s * 64 + lane];
            acc0 += __uint_as_float(v << 16);
            acc1 += __uint_as_float(v & 0xFFFF0000u);
        }
    }
    for (; k < d; ++k) {
        int s = __shfl(myidx, k, 64);
        unsigned int v = msg32[(size_t)s * 64 + lane];
        acc0 += __uint_as_float(v << 16);
        acc1 += __uint_as_float(v & 0xFFFF0000u);
    }
    float inv = 1.0f / (float)max(deg, 1);
    unsigned int bu = base32[(size_t)node * 64 + lane];
    float o0 = acc0 * inv + __uint_as_float(bu << 16);
    float o1 = acc1 * inv + __uint_as_float(bu & 0xFFFF0000u);
    hout32[(size_t)node * 64 + lane] =
        (unsigned int)f2bf(o0) | ((unsigned int)f2bf(o1) << 16);
}

// ---------------- layer-2 aggregate + fused gemm3 ----------------
// Wave computes h2 for its node (regs), stages to LDS; block then computes
// t3[node][20] = h2 @ [Wl3|Wr3] with W3 staged fp32 in LDS.
__global__ __launch_bounds__(256) void agg128_g3(
    const unsigned int* __restrict__ msg32, const int* __restrict__ cnt,
    const unsigned short* __restrict__ colbuf, const unsigned int* __restrict__ base32,
    const float* __restrict__ Wl3, const float* __restrict__ Wr3,
    float* __restrict__ t3, int N) {
    __shared__ float Ws[128 * 20];
    __shared__ float hs[4][132];
    const int tid = threadIdx.x;
    const int lane = tid & 63;
    const int wv = tid >> 6;
    const int node = blockIdx.x * 4 + wv;
    const bool valid = node < N;

    for (int i = tid; i < 2560; i += 256) {
        int k = i / 20, c = i % 20;
        Ws[i] = (c < 10) ? Wl3[k * 10 + c] : Wr3[k * 10 + (c - 10)];
    }

    float o0 = 0.f, o1 = 0.f;
    if (valid) {
        int deg = cnt[node];
        int d = min(deg, CAP);
        const unsigned short* cb = colbuf + (size_t)node * CAP;
        int myidx = (lane < d) ? (int)cb[lane] : 0;
        float acc0 = 0.f, acc1 = 0.f;
        int k = 0;
        for (; k + 16 <= d; k += 16) {
#pragma unroll
            for (int j = 0; j < 16; ++j) {
                int s = __shfl(myidx, k + j, 64);
                unsigned int v = msg32[(size_t)s * 64 + lane];
                acc0 += __uint_as_float(v << 16);
                acc1 += __uint_as_float(v & 0xFFFF0000u);
            }
        }
        for (; k < d; ++k) {
            int s = __shfl(myidx, k, 64);
            unsigned int v = msg32[(size_t)s * 64 + lane];
            acc0 += __uint_as_float(v << 16);
            acc1 += __uint_as_float(v & 0xFFFF0000u);
        }
        float inv = 1.0f / (float)max(deg, 1);
        unsigned int bu = base32[(size_t)node * 64 + lane];
        o0 = acc0 * inv + __uint_as_float(bu << 16);
        o1 = acc1 * inv + __uint_as_float(bu & 0xFFFF0000u);
    }
    hs[wv][lane * 2] = o0;
    hs[wv][lane * 2 + 1] = o1;
    __syncthreads();

    if (tid < 80) {
        int nl = tid / 20, c = tid % 20;
        int n2 = blockIdx.x * 4 + nl;
        if (n2 < N) {
            float acc = 0.f;
#pragma unroll 8
            for (int k = 0; k < 128; ++k) acc += hs[nl][k] * Ws[k * 20 + c];
            t3[(size_t)n2 * 20 + c] = acc;
        }
    }
}

// ---------------- aggregate 10-dim fused with pooling ----------------
// Block handles 256 consecutive nodes (x10 cols); per-graph partial sums in
// LDS, one flush of nonzero bins (sorted batch -> few distinct graphs/block).
__global__ __launch_bounds__(256) void agg10_pool(
    const float* __restrict__ t3, const int* __restrict__ cnt,
    const unsigned short* __restrict__ colbuf, const float* __restrict__ bl3,
    const int* __restrict__ batch,
    float* __restrict__ gsum, float* __restrict__ gcnt, int N) {
    __shared__ float ls[2816];
    for (int i = threadIdx.x; i < 2816; i += 256) ls[i] = 0.f;
    __syncthreads();
    int base0 = blockIdx.x * 256;
    for (int it = 0; it < 10; ++it) {
        int i = it * 256 + threadIdx.x;       // 0..2559
        int n = base0 + i / 10;
        int c = i % 10;
        if (n < N) {
            int deg = cnt[n];
            int d = min(deg, CAP);
            const unsigned short* cb = colbuf + (size_t)n * CAP;
            float acc = 0.f;
            int k = 0;
            for (; k + 4 <= d; k += 4) {
                int s0 = cb[k], s1 = cb[k + 1], s2 = cb[k + 2], s3 = cb[k + 3];
                acc += t3[(size_t)s0 * 20 + c] + t3[(size_t)s1 * 20 + c]
                     + t3[(size_t)s2 * 20 + c] + t3[(size_t)s3 * 20 + c];
            }
            for (; k < d; ++k) acc += t3[(size_t)cb[k] * 20 + c];
            float h = acc / (float)max(deg, 1) + bl3[c] + t3[(size_t)n * 20 + 10 + c];
            int g = batch[n];
            atomicAdd(&ls[g * 10 + c], h);
            if (c == 0) atomicAdd(&ls[2560 + g], 1.0f);
        }
    }
    __syncthreads();
    for (int i = threadIdx.x; i < 2816; i += 256) {
        float v = ls[i];
        if (v != 0.f) {
            if (i < 2560) atomicAdd(&gsum[i], v);
            else          atomicAdd(&gcnt[i - 2560], v);
        }
    }
}

// ---------------- mean + log_softmax ----------------
__global__ void finalize_pool(const float* __restrict__ gsum,
                              const float* __restrict__ gcnt,
                              float* __restrict__ out, int G) {
    int g = blockIdx.x * blockDim.x + threadIdx.x;
    if (g >= G) return;
    float inv = 1.0f / fmaxf(gcnt[g], 1.0f);
    float p[10];
    float m = -1e30f;
#pragma unroll
    for (int c = 0; c < 10; ++c) { p[c] = gsum[g * 10 + c] * inv; m = fmaxf(m, p[c]); }
    float s = 0.f;
#pragma unroll
    for (int c = 0; c < 10; ++c) s += expf(p[c] - m);
    float lse = logf(s);
#pragma unroll
    for (int c = 0; c < 10; ++c) out[g * 10 + c] = p[c] - m - lse;
}

extern "C" void kernel_launch(void* const* d_in, const int* in_sizes, int n_in,
                              void* d_out, int out_size, void* d_ws, size_t ws_size,
                              hipStream_t stream) {
    const float* x    = (const float*)d_in[0];
    const int*   ei   = (const int*)d_in[1];
    const int*   batch= (const int*)d_in[2];
    const float* Wl1  = (const float*)d_in[3];
    const float* bl1  = (const float*)d_in[4];
    const float* Wr1  = (const float*)d_in[5];
    const float* Wl2  = (const float*)d_in[6];
    const float* bl2  = (const float*)d_in[7];
    const float* Wr2  = (const float*)d_in[8];
    const float* Wl3  = (const float*)d_in[9];
    const float* bl3  = (const float*)d_in[10];
    const float* Wr3  = (const float*)d_in[11];
    float* out = (float*)d_out;

    const int N = in_sizes[2];
    const int E = in_sizes[1] / 2;
    const int G = out_size / 10;

    char* ws = (char*)d_ws;
    size_t o = 0;
    int*   cnt    = (int*)(ws + o);   o += (size_t)N * 4;
    float* gsum   = (float*)(ws + o); o += (size_t)G * 10 * 4;
    float* gcnt   = (float*)(ws + o); o += (size_t)G * 4;
    size_t zero_bytes = (o + 255) & ~(size_t)255;
    o = zero_bytes;
    unsigned short* colbuf = (unsigned short*)(ws + o); o += ((size_t)N * CAP * 2 + 255) & ~(size_t)255;  // 4.8 MB
    short*          Wp     = (short*)(ws + o);          o += (size_t)2 * 32768 * 2;                       // 128 KB
    unsigned short* msg    = (unsigned short*)(ws + o); o += (size_t)N * 128 * 2;                         // 12.8 MB
    unsigned short* base   = (unsigned short*)(ws + o); o += (size_t)N * 128 * 2;                         // 12.8 MB
    unsigned short* hbuf   = (unsigned short*)(ws + o); o += (size_t)N * 128 * 2;                         // 12.8 MB
    float*          t3     = (float*)hbuf;              // hbuf dead after gemm2 consumed it (4 MB fits)

    int zero_words = (int)(zero_bytes / 4);
    int zblocks = (zero_words + 255) / 256;
    prep_weights<<<256 + zblocks, 256, 0, stream>>>(Wl1, Wr1, Wl2, Wr2, Wp,
                                                    (int*)ws, zero_words);

    int gblocks = (N + 63) / 64;
    int fblocks = (E + 1023) / 1024;
    int ablocks = (N + 3) / 4;
    // layer 1: fill blocks first, then GEMM blocks
    gemm1_fill<<<fblocks + gblocks, 256, 0, stream>>>(x, Wp, bl1, msg, base, N, fblocks,
                                                      ei, cnt, colbuf, E);
    agg128<<<ablocks, 256, 0, stream>>>((const unsigned int*)msg, cnt, colbuf,
                                        (const unsigned int*)base, (unsigned int*)hbuf, N);
    // layer 2
    gemm_mfma_bf16<<<gblocks, 256, 0, stream>>>(hbuf, Wp + 32768, bl2, msg, base, N);
    // layer-2 aggregate + fused layer-3 GEMM (writes t3 over dead hbuf)
    agg128_g3<<<ablocks, 256, 0, stream>>>((const unsigned int*)msg, cnt, colbuf,
                                           (const unsigned int*)base, Wl3, Wr3, t3, N);
    // layer-3 aggregate + pooling fused
    agg10_pool<<<(N + 255) / 256, 256, 0, stream>>>(t3, cnt, colbuf, bl3, batch,
                                                    gsum, gcnt, N);
    finalize_pool<<<1, 256, 0, stream>>>(gsum, gcnt, out, G);
}

// Round 9
// 289.348 us; speedup vs baseline: 1.1583x; 1.1089x over previous
//
#include <hip/hip_runtime.h>

// GraphSAGE: 3x (project -> mean-aggregate) + mean pool + log_softmax.
// Project-then-aggregate reorder: agg(h) @ Wl == agg(h @ Wl).
// R9 (= R8 + compile fix): fp8-e4m3 msg buffers -> 128 B/node = ONE cacheline
//     per gather (agg is L2 random-line-rate bound; bf16 = 2 lines).
//     cvt_pk_* intrinsics need IMMEDIATE hi-operands -> template<bool HI>.

#define CAP 48

typedef __attribute__((ext_vector_type(8))) short short8;
typedef __attribute__((ext_vector_type(4))) float floatx4;
typedef __attribute__((ext_vector_type(2))) float floatx2;

static __device__ __forceinline__ unsigned short f2bf(float f) {
    unsigned int u = __float_as_uint(f);
    u += 0x7FFFu + ((u >> 16) & 1u);          // round-to-nearest-even
    return (unsigned short)(u >> 16);
}
static __device__ __forceinline__ float bf2f(unsigned short b) {
    return __uint_as_float(((unsigned int)b) << 16);
}

// ---- fp8 pack/unpack: HW cvt on gfx950 (hi-select must be an immediate) ----
#if __has_builtin(__builtin_amdgcn_cvt_pk_f32_fp8) && __has_builtin(__builtin_amdgcn_cvt_pk_fp8_f32)
template<bool HI>
static __device__ __forceinline__ floatx2 fp8x2_to_f32(unsigned int v) {
    return __builtin_amdgcn_cvt_pk_f32_fp8((int)v, HI);
}
static __device__ __forceinline__ unsigned int f32x4_to_fp8(float a, float b, float c, float d) {
    int p = __builtin_amdgcn_cvt_pk_fp8_f32(a, b, 0, false);
    p = __builtin_amdgcn_cvt_pk_fp8_f32(c, d, p, true);
    return (unsigned int)p;
}
#else
static __device__ __forceinline__ float e4m3_to_f32(unsigned int b) {
    float sgn = (b & 0x80) ? -1.f : 1.f;
    unsigned int em = b & 0x7f;
    float mag;
    if (em >= 8) mag = __uint_as_float((((em >> 3) + 120) << 23) | ((em & 7) << 20));
    else mag = (float)em * 0.001953125f;
    return sgn * mag;
}
template<bool HI>
static __device__ __forceinline__ floatx2 fp8x2_to_f32(unsigned int v) {
    unsigned int sh = HI ? 16 : 0;
    floatx2 r;
    r[0] = e4m3_to_f32((v >> sh) & 0xff);
    r[1] = e4m3_to_f32((v >> (sh + 8)) & 0xff);
    return r;
}
static __device__ __forceinline__ unsigned int f32_to_e4m3(float f) {
    unsigned int s = (__float_as_uint(f) >> 24) & 0x80;
    float a = fabsf(f);
    if (a >= 448.f) return s | 0x7e;
    if (a < 0.015625f) return s | (unsigned int)rintf(a * 512.f);
    unsigned int u = __float_as_uint(a);
    u += 0x000FFFFF + ((u >> 20) & 1);
    u &= 0xFFF00000;
    unsigned int e = (u >> 23) - 120;
    if (e > 15) return s | 0x7e;
    return s | (e << 3) | ((u >> 20) & 7);
}
static __device__ __forceinline__ unsigned int f32x4_to_fp8(float a, float b, float c, float d) {
    return f32_to_e4m3(a) | (f32_to_e4m3(b) << 8) | (f32_to_e4m3(c) << 16) | (f32_to_e4m3(d) << 24);
}
#endif

// ---------------- weight prepack (blocks 0..255) + workspace zeroing (tail) ----
__global__ void prep_weights(const float* __restrict__ Wl1, const float* __restrict__ Wr1,
                             const float* __restrict__ Wl2, const float* __restrict__ Wr2,
                             short* __restrict__ Wp,
                             int* __restrict__ zero_base, int zero_words) {
    if (blockIdx.x >= 256) {
        int i = (blockIdx.x - 256) * 256 + threadIdx.x;
        if (i < zero_words) zero_base[i] = 0;
        return;
    }
    int idx = blockIdx.x * 256 + threadIdx.x;      // 65536 total
    int layer = idx >> 15;
    int r = idx & 32767;
    int j = r & 7;
    int l = (r >> 3) & 63;
    int s = (r >> 9) & 3;
    int mf = r >> 11;
    int q = l >> 4, m = l & 15;
    int k = s * 32 + q * 8 + j;
    int f = mf * 16 + m;
    const float* Wl = layer ? Wl2 : Wl1;
    const float* Wr = layer ? Wr2 : Wr1;
    float v = (f < 128) ? Wl[k * 128 + f] : Wr[k * 128 + (f - 128)];
    Wp[idx] = (short)f2bf(v);
}

// ---------------- MFMA GEMM body: msg(fp8)/base(bf16) = A[node][128] @ W[128][256] ----
template<bool IN_F32>
static __device__ __forceinline__ void gemm_body(
    unsigned short* As /* [64*136] */, const void* __restrict__ Ain,
    const short* __restrict__ Wpack, const float* __restrict__ bl,
    unsigned int* __restrict__ msgq, unsigned short* __restrict__ base,
    int N, int blk) {
    const int tid = threadIdx.x;
    const int w = tid >> 6;
    const int l = tid & 63;
    const int q = l >> 4;
    const int m = l & 15;
    const int node0 = blk * 64;

    short8 wf[4][4];   // [mi][s]
#pragma unroll
    for (int mi = 0; mi < 4; ++mi)
#pragma unroll
        for (int s = 0; s < 4; ++s)
            wf[mi][s] = *(const short8*)&Wpack[((((w * 4 + mi) * 4) + s) * 64 + l) * 8];

    if (IN_F32) {
        const float* A = (const float*)Ain;
#pragma unroll
        for (int c = 0; c < 8; ++c) {
            int idx = c * 256 + tid;
            int r = idx >> 5;
            int c4 = idx & 31;
            int row = node0 + r;
            float4 v = make_float4(0.f, 0.f, 0.f, 0.f);
            if (row < N) v = *(const float4*)&A[(size_t)row * 128 + c4 * 4];
            ushort4 p;
            p.x = f2bf(v.x); p.y = f2bf(v.y); p.z = f2bf(v.z); p.w = f2bf(v.w);
            *(ushort4*)&As[r * 136 + c4 * 4] = p;
        }
    } else {
        const unsigned short* A = (const unsigned short*)Ain;
#pragma unroll
        for (int c = 0; c < 4; ++c) {
            int idx = c * 256 + tid;
            int r = idx >> 4;
            int c8 = idx & 15;
            int row = node0 + r;
            short8 v = (short8)0;
            if (row < N) v = *(const short8*)&A[(size_t)row * 128 + c8 * 8];
            *(short8*)&As[r * 136 + c8 * 8] = v;
        }
    }
    __syncthreads();

    floatx4 acc[4][4] = {};    // [mi][nt]
#pragma unroll
    for (int s = 0; s < 4; ++s) {
        short8 bfrag[4];
#pragma unroll
        for (int nt = 0; nt < 4; ++nt)
            bfrag[nt] = *(const short8*)&As[(nt * 16 + m) * 136 + s * 32 + q * 8];
#pragma unroll
        for (int mi = 0; mi < 4; ++mi)
#pragma unroll
            for (int nt = 0; nt < 4; ++nt)
                acc[mi][nt] = __builtin_amdgcn_mfma_f32_16x16x32_bf16(
                    wf[mi][s], bfrag[nt], acc[mi][nt], 0, 0, 0);
    }

#pragma unroll
    for (int mi = 0; mi < 4; ++mi) {
        int f0 = (w * 4 + mi) * 16 + q * 4;
        if (w < 2) {
#pragma unroll
            for (int nt = 0; nt < 4; ++nt) {
                int node = node0 + nt * 16 + m;
                if (node >= N) continue;
                floatx4 a = acc[mi][nt];
                msgq[(size_t)node * 32 + (f0 >> 2)] = f32x4_to_fp8(a[0], a[1], a[2], a[3]);
            }
        } else {
            int fb = f0 - 128;
            float4 bb = *(const float4*)&bl[fb];
#pragma unroll
            for (int nt = 0; nt < 4; ++nt) {
                int node = node0 + nt * 16 + m;
                if (node >= N) continue;
                floatx4 a = acc[mi][nt];
                ushort4 p;
                p.x = f2bf(a[0] + bb.x); p.y = f2bf(a[1] + bb.y);
                p.z = f2bf(a[2] + bb.z); p.w = f2bf(a[3] + bb.w);
                *(ushort4*)&base[(size_t)node * 128 + fb] = p;
            }
        }
    }
}

// layer-1 GEMM with edge-fill blocks FIRST in the grid
__global__ __launch_bounds__(256) void gemm1_fill(
    const float* __restrict__ x, const short* __restrict__ Wpack,
    const float* __restrict__ bl, unsigned int* __restrict__ msgq,
    unsigned short* __restrict__ base, int N, int fblocks,
    const int* __restrict__ ei, int* __restrict__ cnt,
    unsigned short* __restrict__ colbuf, int E) {
    __shared__ unsigned short As[64 * 136];
    if (blockIdx.x >= fblocks) {
        gemm_body<true>(As, x, Wpack, bl, msgq, base, N, blockIdx.x - fblocks);
    } else {
        int e0 = blockIdx.x * 1024 + threadIdx.x;    // 4 edges per thread
        int src[4], dst[4];
#pragma unroll
        for (int k = 0; k < 4; ++k) {
            int e = e0 + k * 256;
            bool ok = e < E;
            src[k] = ok ? ei[e] : -1;
            dst[k] = ok ? ei[E + e] : 0;
        }
#pragma unroll
        for (int k = 0; k < 4; ++k) {
            if (src[k] >= 0) {
                int slot = atomicAdd(&cnt[dst[k]], 1);
                if (slot < CAP) colbuf[dst[k] * CAP + slot] = (unsigned short)src[k];
            }
        }
    }
}

__global__ __launch_bounds__(256) void gemm_mfma_bf16(
    const unsigned short* __restrict__ Ain, const short* __restrict__ Wpack,
    const float* __restrict__ bl, unsigned int* __restrict__ msgq,
    unsigned short* __restrict__ base, int N) {
    __shared__ unsigned short As[64 * 136];
    gemm_body<false>(As, Ain, Wpack, bl, msgq, base, N, blockIdx.x);
}

// ---------------- aggregate 128-dim: wave per node, fp8 msg, 2 nbrs/iter ----
// msg8: [N][32] uints (4 fp8 features each). Half-wave per neighbor:
// lanes 0-31 neighbor k, lanes 32-63 neighbor k+1, combine via shfl_xor(32).
__global__ __launch_bounds__(256) void agg128(
    const unsigned int* __restrict__ msg8, const int* __restrict__ cnt,
    const unsigned short* __restrict__ colbuf, const uint2* __restrict__ base64,
    ushort4* __restrict__ hout, int N) {
    int lane = threadIdx.x & 63;
    int node = blockIdx.x * 4 + (threadIdx.x >> 6);
    if (node >= N) return;
    int deg = cnt[node];
    int d = min(deg, CAP);
    const unsigned short* cb = colbuf + (size_t)node * CAP;
    int myidx = (lane < d) ? (int)cb[lane] : 0;
    int half = lane >> 5;        // which neighbor of the pair
    int fl = lane & 31;          // feature-quad index (features 4*fl..4*fl+3)
    float a0 = 0.f, a1 = 0.f, a2 = 0.f, a3 = 0.f;
    int k = 0;
    for (; k + 16 <= d; k += 16) {           // 8 lines in flight
        unsigned int vv[8];
#pragma unroll
        for (int j = 0; j < 8; ++j) {
            int s = __shfl(myidx, k + 2 * j + half, 64);
            vv[j] = msg8[(size_t)s * 32 + fl];
        }
#pragma unroll
        for (int j = 0; j < 8; ++j) {
            floatx2 lo = fp8x2_to_f32<false>(vv[j]);
            floatx2 hi = fp8x2_to_f32<true>(vv[j]);
            a0 += lo[0]; a1 += lo[1]; a2 += hi[0]; a3 += hi[1];
        }
    }
    for (; k + 2 <= d; k += 2) {
        int s = __shfl(myidx, k + half, 64);
        unsigned int v = msg8[(size_t)s * 32 + fl];
        floatx2 lo = fp8x2_to_f32<false>(v);
        floatx2 hi = fp8x2_to_f32<true>(v);
        a0 += lo[0]; a1 += lo[1]; a2 += hi[0]; a3 += hi[1];
    }
    if (k < d) {                              // odd tail: half 0 only
        int s = __shfl(myidx, k, 64);
        unsigned int v = (half == 0) ? msg8[(size_t)s * 32 + fl] : 0u;
        floatx2 lo = fp8x2_to_f32<false>(v);
        floatx2 hi = fp8x2_to_f32<true>(v);
        a0 += lo[0]; a1 += lo[1]; a2 += hi[0]; a3 += hi[1];
    }
    a0 += __shfl_xor(a0, 32, 64);
    a1 += __shfl_xor(a1, 32, 64);
    a2 += __shfl_xor(a2, 32, 64);
    a3 += __shfl_xor(a3, 32, 64);
    if (half == 0) {
        float inv = 1.0f / (float)max(deg, 1);
        uint2 bu = base64[(size_t)node * 32 + fl];
        float b0 = bf2f((unsigned short)(bu.x & 0xFFFF));
        float b1 = bf2f((unsigned short)(bu.x >> 16));
        float b2 = bf2f((unsigned short)(bu.y & 0xFFFF));
        float b3 = bf2f((unsigned short)(bu.y >> 16));
        ushort4 p;
        p.x = f2bf(a0 * inv + b0); p.y = f2bf(a1 * inv + b1);
        p.z = f2bf(a2 * inv + b2); p.w = f2bf(a3 * inv + b3);
        hout[(size_t)node * 32 + fl] = p;
    }
}

// ---------------- layer-3 GEMM: T3[N,20] = h(bf16)[N,128] @ [Wl3 | Wr3] ----------
__global__ __launch_bounds__(256) void gemm3(
    const unsigned short* __restrict__ h, const float* __restrict__ Wl,
    const float* __restrict__ Wr, float* __restrict__ t3, int N) {
    __shared__ float hs[64][136];
    __shared__ float Ws[128][20];
    const int tid = threadIdx.x;
    const int row0 = blockIdx.x * 64;
    for (int i = tid; i < 128 * 20; i += 256) {
        int k = i / 20, c = i % 20;
        Ws[k][c] = (c < 10) ? Wl[k * 10 + c] : Wr[k * 10 + (c - 10)];
    }
#pragma unroll
    for (int ch = 0; ch < 4; ++ch) {
        int idx = ch * 256 + tid;
        int r = idx >> 4;
        int c8 = idx & 15;
        int row = row0 + r;
        short8 v = (short8)0;
        if (row < N) v = *(const short8*)&h[(size_t)row * 128 + c8 * 8];
#pragma unroll
        for (int i = 0; i < 8; ++i)
            hs[r][c8 * 8 + i] = bf2f((unsigned short)v[i]);
    }
    __syncthreads();
    for (int i = tid; i < 64 * 20; i += 256) {
        int r = i / 20, c = i % 20;
        int row = row0 + r;
        if (row >= N) continue;
        float acc = 0.f;
#pragma unroll 16
        for (int k = 0; k < 128; ++k) acc += hs[r][k] * Ws[k][c];
        t3[(size_t)row * 20 + c] = acc;
    }
}

// ---------------- aggregate 10-dim fused with pooling ----------------
__global__ __launch_bounds__(256) void agg10_pool(
    const float* __restrict__ t3, const int* __restrict__ cnt,
    const unsigned short* __restrict__ colbuf, const float* __restrict__ bl3,
    const int* __restrict__ batch,
    float* __restrict__ gsum, float* __restrict__ gcnt, int N) {
    __shared__ float ls[2816];
    for (int i = threadIdx.x; i < 2816; i += 256) ls[i] = 0.f;
    __syncthreads();
    int base0 = blockIdx.x * 256;
    for (int it = 0; it < 10; ++it) {
        int i = it * 256 + threadIdx.x;       // 0..2559
        int n = base0 + i / 10;
        int c = i % 10;
        if (n < N) {
            int deg = cnt[n];
            int d = min(deg, CAP);
            const unsigned short* cb = colbuf + (size_t)n * CAP;
            float acc = 0.f;
            int k = 0;
            for (; k + 4 <= d; k += 4) {
                int s0 = cb[k], s1 = cb[k + 1], s2 = cb[k + 2], s3 = cb[k + 3];
                acc += t3[(size_t)s0 * 20 + c] + t3[(size_t)s1 * 20 + c]
                     + t3[(size_t)s2 * 20 + c] + t3[(size_t)s3 * 20 + c];
            }
            for (; k < d; ++k) acc += t3[(size_t)cb[k] * 20 + c];
            float h = acc / (float)max(deg, 1) + bl3[c] + t3[(size_t)n * 20 + 10 + c];
            int g = batch[n];
            atomicAdd(&ls[g * 10 + c], h);
            if (c == 0) atomicAdd(&ls[2560 + g], 1.0f);
        }
    }
    __syncthreads();
    for (int i = threadIdx.x; i < 2816; i += 256) {
        float v = ls[i];
        if (v != 0.f) {
            if (i < 2560) atomicAdd(&gsum[i], v);
            else          atomicAdd(&gcnt[i - 2560], v);
        }
    }
}

// ---------------- mean + log_softmax ----------------
__global__ void finalize_pool(const float* __restrict__ gsum,
                              const float* __restrict__ gcnt,
                              float* __restrict__ out, int G) {
    int g = blockIdx.x * blockDim.x + threadIdx.x;
    if (g >= G) return;
    float inv = 1.0f / fmaxf(gcnt[g], 1.0f);
    float p[10];
    float m = -1e30f;
#pragma unroll
    for (int c = 0; c < 10; ++c) { p[c] = gsum[g * 10 + c] * inv; m = fmaxf(m, p[c]); }
    float s = 0.f;
#pragma unroll
    for (int c = 0; c < 10; ++c) s += expf(p[c] - m);
    float lse = logf(s);
#pragma unroll
    for (int c = 0; c < 10; ++c) out[g * 10 + c] = p[c] - m - lse;
}

extern "C" void kernel_launch(void* const* d_in, const int* in_sizes, int n_in,
                              void* d_out, int out_size, void* d_ws, size_t ws_size,
                              hipStream_t stream) {
    const float* x    = (const float*)d_in[0];
    const int*   ei   = (const int*)d_in[1];
    const int*   batch= (const int*)d_in[2];
    const float* Wl1  = (const float*)d_in[3];
    const float* bl1  = (const float*)d_in[4];
    const float* Wr1  = (const float*)d_in[5];
    const float* Wl2  = (const float*)d_in[6];
    const float* bl2  = (const float*)d_in[7];
    const float* Wr2  = (const float*)d_in[8];
    const float* Wl3  = (const float*)d_in[9];
    const float* bl3  = (const float*)d_in[10];
    const float* Wr3  = (const float*)d_in[11];
    float* out = (float*)d_out;

    const int N = in_sizes[2];
    const int E = in_sizes[1] / 2;
    const int G = out_size / 10;

    char* ws = (char*)d_ws;
    size_t o = 0;
    int*   cnt    = (int*)(ws + o);   o += (size_t)N * 4;
    float* gsum   = (float*)(ws + o); o += (size_t)G * 10 * 4;
    float* gcnt   = (float*)(ws + o); o += (size_t)G * 4;
    size_t zero_bytes = (o + 255) & ~(size_t)255;
    o = zero_bytes;
    unsigned short* colbuf = (unsigned short*)(ws + o); o += ((size_t)N * CAP * 2 + 255) & ~(size_t)255;  // 4.8 MB
    short*          Wp     = (short*)(ws + o);          o += (size_t)2 * 32768 * 2;                       // 128 KB
    unsigned int*   msgq   = (unsigned int*)(ws + o);   o += (size_t)N * 128;                             // 6.4 MB fp8
    unsigned short* base   = (unsigned short*)(ws + o); o += (size_t)N * 128 * 2;                         // 12.8 MB
    unsigned short* hbuf   = (unsigned short*)(ws + o); o += (size_t)N * 128 * 2;                         // 12.8 MB
    float*          t3     = (float*)(ws + o);          o += (size_t)N * 20 * 4;                          // 4 MB

    int zero_words = (int)(zero_bytes / 4);
    int zblocks = (zero_words + 255) / 256;
    prep_weights<<<256 + zblocks, 256, 0, stream>>>(Wl1, Wr1, Wl2, Wr2, Wp,
                                                    (int*)ws, zero_words);

    int gblocks = (N + 63) / 64;
    int fblocks = (E + 1023) / 1024;
    int ablocks = (N + 3) / 4;
    // layer 1: fill blocks first, then GEMM blocks
    gemm1_fill<<<fblocks + gblocks, 256, 0, stream>>>(x, Wp, bl1, msgq, base, N, fblocks,
                                                      ei, cnt, colbuf, E);
    agg128<<<ablocks, 256, 0, stream>>>(msgq, cnt, colbuf, (const uint2*)base,
                                        (ushort4*)hbuf, N);
    // layer 2
    gemm_mfma_bf16<<<gblocks, 256, 0, stream>>>(hbuf, Wp + 32768, bl2, msgq, base, N);
    agg128<<<ablocks, 256, 0, stream>>>(msgq, cnt, colbuf, (const uint2*)base,
                                        (ushort4*)hbuf, N);
    // layer 3
    gemm3<<<gblocks, 256, 0, stream>>>(hbuf, Wl3, Wr3, t3, N);
    // layer-3 aggregate + pooling fused
    agg10_pool<<<(N + 255) / 256, 256, 0, stream>>>(t3, cnt, colbuf, bl3, batch,
                                                    gsum, gcnt, N);
    finalize_pool<<<1, 256, 0, stream>>>(gsum, gcnt, out, G);
}

// Round 10
// 267.923 us; speedup vs baseline: 1.2510x; 1.0800x over previous
//
#include <hip/hip_runtime.h>

// GraphSAGE: 3x (project -> mean-aggregate) + mean pool + log_softmax.
// Project-then-aggregate reorder: agg(h) @ Wl == agg(h @ Wl).
// R10: agg block has been flat ~170us since R2 regardless of payload ->
//      outstanding-miss limited, not bytes. New agg128: 4 nodes/wave
//      (quarter-wave x uint2 = 1 line/node/instr -> 4 lines per instr,
//      64 in flight per wave), zero-row padding kills all tails/guards,
//      no cross-lane reduction (lane owns its 8 features).

#define CAP 48

typedef __attribute__((ext_vector_type(8))) short short8;
typedef __attribute__((ext_vector_type(4))) float floatx4;
typedef __attribute__((ext_vector_type(2))) float floatx2;

static __device__ __forceinline__ unsigned short f2bf(float f) {
    unsigned int u = __float_as_uint(f);
    u += 0x7FFFu + ((u >> 16) & 1u);          // round-to-nearest-even
    return (unsigned short)(u >> 16);
}
static __device__ __forceinline__ float bf2f(unsigned short b) {
    return __uint_as_float(((unsigned int)b) << 16);
}

// ---- fp8 pack/unpack: HW cvt on gfx950 (hi-select must be an immediate) ----
#if __has_builtin(__builtin_amdgcn_cvt_pk_f32_fp8) && __has_builtin(__builtin_amdgcn_cvt_pk_fp8_f32)
template<bool HI>
static __device__ __forceinline__ floatx2 fp8x2_to_f32(unsigned int v) {
    return __builtin_amdgcn_cvt_pk_f32_fp8((int)v, HI);
}
static __device__ __forceinline__ unsigned int f32x4_to_fp8(float a, float b, float c, float d) {
    int p = __builtin_amdgcn_cvt_pk_fp8_f32(a, b, 0, false);
    p = __builtin_amdgcn_cvt_pk_fp8_f32(c, d, p, true);
    return (unsigned int)p;
}
#else
static __device__ __forceinline__ float e4m3_to_f32(unsigned int b) {
    float sgn = (b & 0x80) ? -1.f : 1.f;
    unsigned int em = b & 0x7f;
    float mag;
    if (em >= 8) mag = __uint_as_float((((em >> 3) + 120) << 23) | ((em & 7) << 20));
    else mag = (float)em * 0.001953125f;
    return sgn * mag;
}
template<bool HI>
static __device__ __forceinline__ floatx2 fp8x2_to_f32(unsigned int v) {
    unsigned int sh = HI ? 16 : 0;
    floatx2 r;
    r[0] = e4m3_to_f32((v >> sh) & 0xff);
    r[1] = e4m3_to_f32((v >> (sh + 8)) & 0xff);
    return r;
}
static __device__ __forceinline__ unsigned int f32_to_e4m3(float f) {
    unsigned int s = (__float_as_uint(f) >> 24) & 0x80;
    float a = fabsf(f);
    if (a >= 448.f) return s | 0x7e;
    if (a < 0.015625f) return s | (unsigned int)rintf(a * 512.f);
    unsigned int u = __float_as_uint(a);
    u += 0x000FFFFF + ((u >> 20) & 1);
    u &= 0xFFF00000;
    unsigned int e = (u >> 23) - 120;
    if (e > 15) return s | 0x7e;
    return s | (e << 3) | ((u >> 20) & 7);
}
static __device__ __forceinline__ unsigned int f32x4_to_fp8(float a, float b, float c, float d) {
    return f32_to_e4m3(a) | (f32_to_e4m3(b) << 8) | (f32_to_e4m3(c) << 16) | (f32_to_e4m3(d) << 24);
}
#endif

// ---------------- weight prepack (blocks 0..255) + workspace zeroing (tail) ----
// Block 256 additionally zeros the msgq zero-row (row N, 32 uints).
__global__ void prep_weights(const float* __restrict__ Wl1, const float* __restrict__ Wr1,
                             const float* __restrict__ Wl2, const float* __restrict__ Wr2,
                             short* __restrict__ Wp,
                             int* __restrict__ zero_base, int zero_words,
                             unsigned int* __restrict__ msgq, int N) {
    if (blockIdx.x >= 256) {
        int i = (blockIdx.x - 256) * 256 + threadIdx.x;
        if (i < zero_words) zero_base[i] = 0;
        if (blockIdx.x == 256 && threadIdx.x < 32)
            msgq[(size_t)N * 32 + threadIdx.x] = 0;   // fp8 zero-row for padding slots
        return;
    }
    int idx = blockIdx.x * 256 + threadIdx.x;      // 65536 total
    int layer = idx >> 15;
    int r = idx & 32767;
    int j = r & 7;
    int l = (r >> 3) & 63;
    int s = (r >> 9) & 3;
    int mf = r >> 11;
    int q = l >> 4, m = l & 15;
    int k = s * 32 + q * 8 + j;
    int f = mf * 16 + m;
    const float* Wl = layer ? Wl2 : Wl1;
    const float* Wr = layer ? Wr2 : Wr1;
    float v = (f < 128) ? Wl[k * 128 + f] : Wr[k * 128 + (f - 128)];
    Wp[idx] = (short)f2bf(v);
}

// ---------------- MFMA GEMM body: msg(fp8)/base(bf16) = A[node][128] @ W[128][256] ----
template<bool IN_F32>
static __device__ __forceinline__ void gemm_body(
    unsigned short* As /* [64*136] */, const void* __restrict__ Ain,
    const short* __restrict__ Wpack, const float* __restrict__ bl,
    unsigned int* __restrict__ msgq, unsigned short* __restrict__ base,
    int N, int blk) {
    const int tid = threadIdx.x;
    const int w = tid >> 6;
    const int l = tid & 63;
    const int q = l >> 4;
    const int m = l & 15;
    const int node0 = blk * 64;

    short8 wf[4][4];   // [mi][s]
#pragma unroll
    for (int mi = 0; mi < 4; ++mi)
#pragma unroll
        for (int s = 0; s < 4; ++s)
            wf[mi][s] = *(const short8*)&Wpack[((((w * 4 + mi) * 4) + s) * 64 + l) * 8];

    if (IN_F32) {
        const float* A = (const float*)Ain;
#pragma unroll
        for (int c = 0; c < 8; ++c) {
            int idx = c * 256 + tid;
            int r = idx >> 5;
            int c4 = idx & 31;
            int row = node0 + r;
            float4 v = make_float4(0.f, 0.f, 0.f, 0.f);
            if (row < N) v = *(const float4*)&A[(size_t)row * 128 + c4 * 4];
            ushort4 p;
            p.x = f2bf(v.x); p.y = f2bf(v.y); p.z = f2bf(v.z); p.w = f2bf(v.w);
            *(ushort4*)&As[r * 136 + c4 * 4] = p;
        }
    } else {
        const unsigned short* A = (const unsigned short*)Ain;
#pragma unroll
        for (int c = 0; c < 4; ++c) {
            int idx = c * 256 + tid;
            int r = idx >> 4;
            int c8 = idx & 15;
            int row = node0 + r;
            short8 v = (short8)0;
            if (row < N) v = *(const short8*)&A[(size_t)row * 128 + c8 * 8];
            *(short8*)&As[r * 136 + c8 * 8] = v;
        }
    }
    __syncthreads();

    floatx4 acc[4][4] = {};    // [mi][nt]
#pragma unroll
    for (int s = 0; s < 4; ++s) {
        short8 bfrag[4];
#pragma unroll
        for (int nt = 0; nt < 4; ++nt)
            bfrag[nt] = *(const short8*)&As[(nt * 16 + m) * 136 + s * 32 + q * 8];
#pragma unroll
        for (int mi = 0; mi < 4; ++mi)
#pragma unroll
            for (int nt = 0; nt < 4; ++nt)
                acc[mi][nt] = __builtin_amdgcn_mfma_f32_16x16x32_bf16(
                    wf[mi][s], bfrag[nt], acc[mi][nt], 0, 0, 0);
    }

#pragma unroll
    for (int mi = 0; mi < 4; ++mi) {
        int f0 = (w * 4 + mi) * 16 + q * 4;
        if (w < 2) {
#pragma unroll
            for (int nt = 0; nt < 4; ++nt) {
                int node = node0 + nt * 16 + m;
                if (node >= N) continue;
                floatx4 a = acc[mi][nt];
                msgq[(size_t)node * 32 + (f0 >> 2)] = f32x4_to_fp8(a[0], a[1], a[2], a[3]);
            }
        } else {
            int fb = f0 - 128;
            float4 bb = *(const float4*)&bl[fb];
#pragma unroll
            for (int nt = 0; nt < 4; ++nt) {
                int node = node0 + nt * 16 + m;
                if (node >= N) continue;
                floatx4 a = acc[mi][nt];
                ushort4 p;
                p.x = f2bf(a[0] + bb.x); p.y = f2bf(a[1] + bb.y);
                p.z = f2bf(a[2] + bb.z); p.w = f2bf(a[3] + bb.w);
                *(ushort4*)&base[(size_t)node * 128 + fb] = p;
            }
        }
    }
}

// layer-1 GEMM with edge-fill blocks FIRST in the grid
__global__ __launch_bounds__(256) void gemm1_fill(
    const float* __restrict__ x, const short* __restrict__ Wpack,
    const float* __restrict__ bl, unsigned int* __restrict__ msgq,
    unsigned short* __restrict__ base, int N, int fblocks,
    const int* __restrict__ ei, int* __restrict__ cnt,
    unsigned short* __restrict__ colbuf, int E) {
    __shared__ unsigned short As[64 * 136];
    if (blockIdx.x >= fblocks) {
        gemm_body<true>(As, x, Wpack, bl, msgq, base, N, blockIdx.x - fblocks);
    } else {
        int e0 = blockIdx.x * 1024 + threadIdx.x;    // 4 edges per thread
        int src[4], dst[4];
#pragma unroll
        for (int k = 0; k < 4; ++k) {
            int e = e0 + k * 256;
            bool ok = e < E;
            src[k] = ok ? ei[e] : -1;
            dst[k] = ok ? ei[E + e] : 0;
        }
#pragma unroll
        for (int k = 0; k < 4; ++k) {
            if (src[k] >= 0) {
                int slot = atomicAdd(&cnt[dst[k]], 1);
                if (slot < CAP) colbuf[dst[k] * CAP + slot] = (unsigned short)src[k];
            }
        }
    }
}

__global__ __launch_bounds__(256) void gemm_mfma_bf16(
    const unsigned short* __restrict__ Ain, const short* __restrict__ Wpack,
    const float* __restrict__ bl, unsigned int* __restrict__ msgq,
    unsigned short* __restrict__ base, int N) {
    __shared__ unsigned short As[64 * 136];
    gemm_body<false>(As, Ain, Wpack, bl, msgq, base, N, blockIdx.x);
}

// ---------------- aggregate 128-dim: 4 nodes per WAVE (quarter-wave each) ----
// msg8: (N+1) rows x 16 uint2 (row N = zeros, used for padding slots).
// Lane la (0..15 within quarter) owns features 8la..8la+7 end-to-end.
// Each gather instruction touches 4 lines (one per quarter); 16 unrolled
// loads/batch -> 64 lines in flight per wave.
__global__ __launch_bounds__(256) void agg128(
    const uint2* __restrict__ msg8, const int* __restrict__ cnt,
    const unsigned short* __restrict__ colbuf, const uint4* __restrict__ base128,
    uint4* __restrict__ hout, int N) {
    const int lane = threadIdx.x & 63;
    const int wv = threadIdx.x >> 6;
    const int la = lane & 15;
    const int qb = lane & 48;                       // quarter base lane
    const int node = blockIdx.x * 16 + wv * 4 + (lane >> 4);
    const bool valid = node < N;
    const int nodec = valid ? node : N - 1;
    const int deg = cnt[nodec];
    const int d = valid ? min(deg, CAP) : 0;
    const unsigned short* cb = colbuf + (size_t)nodec * CAP;

    floatx2 a0 = {0.f, 0.f}, a1 = a0, a2 = a0, a3 = a0;
    int nb = (d + 15) >> 4;
    for (int b = 0; b < nb; ++b) {
        int slot = b * 16 + la;
        int idx = (slot < d) ? (int)cb[slot] : N;   // N = zero row
        uint2 vv[16];
#pragma unroll
        for (int j = 0; j < 16; ++j) {
            int s = __shfl(idx, qb + j, 64);
            vv[j] = msg8[(size_t)s * 16 + la];
        }
#pragma unroll
        for (int j = 0; j < 16; ++j) {
            a0 += fp8x2_to_f32<false>(vv[j].x);
            a1 += fp8x2_to_f32<true >(vv[j].x);
            a2 += fp8x2_to_f32<false>(vv[j].y);
            a3 += fp8x2_to_f32<true >(vv[j].y);
        }
    }
    if (valid) {
        float inv = 1.0f / (float)max(deg, 1);
        uint4 bu = base128[(size_t)node * 16 + la];
        uint4 p;
        p.x = (unsigned int)f2bf(a0[0] * inv + bf2f((unsigned short)(bu.x & 0xFFFF)))
            | ((unsigned int)f2bf(a0[1] * inv + bf2f((unsigned short)(bu.x >> 16))) << 16);
        p.y = (unsigned int)f2bf(a1[0] * inv + bf2f((unsigned short)(bu.y & 0xFFFF)))
            | ((unsigned int)f2bf(a1[1] * inv + bf2f((unsigned short)(bu.y >> 16))) << 16);
        p.z = (unsigned int)f2bf(a2[0] * inv + bf2f((unsigned short)(bu.z & 0xFFFF)))
            | ((unsigned int)f2bf(a2[1] * inv + bf2f((unsigned short)(bu.z >> 16))) << 16);
        p.w = (unsigned int)f2bf(a3[0] * inv + bf2f((unsigned short)(bu.w & 0xFFFF)))
            | ((unsigned int)f2bf(a3[1] * inv + bf2f((unsigned short)(bu.w >> 16))) << 16);
        hout[(size_t)node * 16 + la] = p;
    }
}

// ---------------- layer-3 GEMM: T3[N,20] = h(bf16)[N,128] @ [Wl3 | Wr3] ----------
__global__ __launch_bounds__(256) void gemm3(
    const unsigned short* __restrict__ h, const float* __restrict__ Wl,
    const float* __restrict__ Wr, float* __restrict__ t3, int N) {
    __shared__ float hs[64][136];
    __shared__ float Ws[128][20];
    const int tid = threadIdx.x;
    const int row0 = blockIdx.x * 64;
    for (int i = tid; i < 128 * 20; i += 256) {
        int k = i / 20, c = i % 20;
        Ws[k][c] = (c < 10) ? Wl[k * 10 + c] : Wr[k * 10 + (c - 10)];
    }
#pragma unroll
    for (int ch = 0; ch < 4; ++ch) {
        int idx = ch * 256 + tid;
        int r = idx >> 4;
        int c8 = idx & 15;
        int row = row0 + r;
        short8 v = (short8)0;
        if (row < N) v = *(const short8*)&h[(size_t)row * 128 + c8 * 8];
#pragma unroll
        for (int i = 0; i < 8; ++i)
            hs[r][c8 * 8 + i] = bf2f((unsigned short)v[i]);
    }
    __syncthreads();
    for (int i = tid; i < 64 * 20; i += 256) {
        int r = i / 20, c = i % 20;
        int row = row0 + r;
        if (row >= N) continue;
        float acc = 0.f;
#pragma unroll 16
        for (int k = 0; k < 128; ++k) acc += hs[r][k] * Ws[k][c];
        t3[(size_t)row * 20 + c] = acc;
    }
}

// ---------------- aggregate 10-dim fused with pooling ----------------
__global__ __launch_bounds__(256) void agg10_pool(
    const float* __restrict__ t3, const int* __restrict__ cnt,
    const unsigned short* __restrict__ colbuf, const float* __restrict__ bl3,
    const int* __restrict__ batch,
    float* __restrict__ gsum, float* __restrict__ gcnt, int N) {
    __shared__ float ls[2816];
    for (int i = threadIdx.x; i < 2816; i += 256) ls[i] = 0.f;
    __syncthreads();
    int base0 = blockIdx.x * 256;
    for (int it = 0; it < 10; ++it) {
        int i = it * 256 + threadIdx.x;       // 0..2559
        int n = base0 + i / 10;
        int c = i % 10;
        if (n < N) {
            int deg = cnt[n];
            int d = min(deg, CAP);
            const unsigned short* cb = colbuf + (size_t)n * CAP;
            float acc = 0.f;
            int k = 0;
            for (; k + 4 <= d; k += 4) {
                int s0 = cb[k], s1 = cb[k + 1], s2 = cb[k + 2], s3 = cb[k + 3];
                acc += t3[(size_t)s0 * 20 + c] + t3[(size_t)s1 * 20 + c]
                     + t3[(size_t)s2 * 20 + c] + t3[(size_t)s3 * 20 + c];
            }
            for (; k < d; ++k) acc += t3[(size_t)cb[k] * 20 + c];
            float h = acc / (float)max(deg, 1) + bl3[c] + t3[(size_t)n * 20 + 10 + c];
            int g = batch[n];
            atomicAdd(&ls[g * 10 + c], h);
            if (c == 0) atomicAdd(&ls[2560 + g], 1.0f);
        }
    }
    __syncthreads();
    for (int i = threadIdx.x; i < 2816; i += 256) {
        float v = ls[i];
        if (v != 0.f) {
            if (i < 2560) atomicAdd(&gsum[i], v);
            else          atomicAdd(&gcnt[i - 2560], v);
        }
    }
}

// ---------------- mean + log_softmax ----------------
__global__ void finalize_pool(const float* __restrict__ gsum,
                              const float* __restrict__ gcnt,
                              float* __restrict__ out, int G) {
    int g = blockIdx.x * blockDim.x + threadIdx.x;
    if (g >= G) return;
    float inv = 1.0f / fmaxf(gcnt[g], 1.0f);
    float p[10];
    float m = -1e30f;
#pragma unroll
    for (int c = 0; c < 10; ++c) { p[c] = gsum[g * 10 + c] * inv; m = fmaxf(m, p[c]); }
    float s = 0.f;
#pragma unroll
    for (int c = 0; c < 10; ++c) s += expf(p[c] - m);
    float lse = logf(s);
#pragma unroll
    for (int c = 0; c < 10; ++c) out[g * 10 + c] = p[c] - m - lse;
}

extern "C" void kernel_launch(void* const* d_in, const int* in_sizes, int n_in,
                              void* d_out, int out_size, void* d_ws, size_t ws_size,
                              hipStream_t stream) {
    const float* x    = (const float*)d_in[0];
    const int*   ei   = (const int*)d_in[1];
    const int*   batch= (const int*)d_in[2];
    const float* Wl1  = (const float*)d_in[3];
    const float* bl1  = (const float*)d_in[4];
    const float* Wr1  = (const float*)d_in[5];
    const float* Wl2  = (const float*)d_in[6];
    const float* bl2  = (const float*)d_in[7];
    const float* Wr2  = (const float*)d_in[8];
    const float* Wl3  = (const float*)d_in[9];
    const float* bl3  = (const float*)d_in[10];
    const float* Wr3  = (const float*)d_in[11];
    float* out = (float*)d_out;

    const int N = in_sizes[2];
    const int E = in_sizes[1] / 2;
    const int G = out_size / 10;

    char* ws = (char*)d_ws;
    size_t o = 0;
    int*   cnt    = (int*)(ws + o);   o += (size_t)N * 4;
    float* gsum   = (float*)(ws + o); o += (size_t)G * 10 * 4;
    float* gcnt   = (float*)(ws + o); o += (size_t)G * 4;
    size_t zero_bytes = (o + 255) & ~(size_t)255;
    o = zero_bytes;
    unsigned short* colbuf = (unsigned short*)(ws + o); o += ((size_t)N * CAP * 2 + 255) & ~(size_t)255;  // 4.8 MB
    short*          Wp     = (short*)(ws + o);          o += (size_t)2 * 32768 * 2;                       // 128 KB
    unsigned int*   msgq   = (unsigned int*)(ws + o);   o += (size_t)(N + 1) * 128;                       // 6.4 MB fp8 (+zero row)
    unsigned short* base   = (unsigned short*)(ws + o); o += (size_t)N * 128 * 2;                         // 12.8 MB
    unsigned short* hbuf   = (unsigned short*)(ws + o); o += (size_t)N * 128 * 2;                         // 12.8 MB
    float*          t3     = (float*)(ws + o);          o += (size_t)N * 20 * 4;                          // 4 MB

    int zero_words = (int)(zero_bytes / 4);
    int zblocks = (zero_words + 255) / 256;
    prep_weights<<<256 + zblocks, 256, 0, stream>>>(Wl1, Wr1, Wl2, Wr2, Wp,
                                                    (int*)ws, zero_words, msgq, N);

    int gblocks = (N + 63) / 64;
    int fblocks = (E + 1023) / 1024;
    int ablocks = (N + 15) / 16;
    // layer 1: fill blocks first, then GEMM blocks
    gemm1_fill<<<fblocks + gblocks, 256, 0, stream>>>(x, Wp, bl1, msgq, base, N, fblocks,
                                                      ei, cnt, colbuf, E);
    agg128<<<ablocks, 256, 0, stream>>>((const uint2*)msgq, cnt, colbuf,
                                        (const uint4*)base, (uint4*)hbuf, N);
    // layer 2
    gemm_mfma_bf16<<<gblocks, 256, 0, stream>>>(hbuf, Wp + 32768, bl2, msgq, base, N);
    agg128<<<ablocks, 256, 0, stream>>>((const uint2*)msgq, cnt, colbuf,
                                        (const uint4*)base, (uint4*)hbuf, N);
    // layer 3
    gemm3<<<gblocks, 256, 0, stream>>>(hbuf, Wl3, Wr3, t3, N);
    // layer-3 aggregate + pooling fused
    agg10_pool<<<(N + 255) / 256, 256, 0, stream>>>(t3, cnt, colbuf, bl3, batch,
                                                    gsum, gcnt, N);
    finalize_pool<<<1, 256, 0, stream>>>(gsum, gcnt, out, G);
}